// Round 1
// baseline (59.980 us; speedup 1.0000x reference)
//
#include <hip/hip_runtime.h>
#include <math.h>

// ---------------------------------------------------------------------------
// Net: conv2d(3->1,5x5,VALID) + bias -> xor_linear(784->128) -> step ->
//      xor_linear(128->64) -> step -> xor_linear(64->10) -> log_softmax
//
// xor_linear(X,W,b) = sum_j xor(Xb_j, Wb_j) + b - in/2
//                   = popcount(Xbits ^ Wbits) + b - in/2   (binary vectors)
// All pre-activations are exact small integers -> bit-exact thresholding.
// ---------------------------------------------------------------------------

#define NW1 25   // 784 bits -> 25 u32 words

// Pack W1 (128x784) -> w1t[25][128] u32 (word-major/transposed, coalesced),
//      W2 (64x128)  -> w2b[2][64]  u64,
//      W3 (10x64)   -> w3b[10]     u64.
__global__ void pack_weights(const float* __restrict__ W1,
                             const float* __restrict__ W2,
                             const float* __restrict__ W3,
                             unsigned* __restrict__ w1t,
                             unsigned long long* __restrict__ w2b,
                             unsigned long long* __restrict__ w3b) {
    int t = blockIdx.x * 256 + threadIdx.x;
    if (t < NW1 * 128) {
        int j = t / 128, i = t % 128;          // word j of row i
        unsigned v = 0;
        int base = j * 32;
        #pragma unroll 4
        for (int b = 0; b < 32; ++b) {
            int col = base + b;
            if (col < 784 && W1[i * 784 + col] != 0.0f) v |= (1u << b);
        }
        w1t[j * 128 + i] = v;
    } else if (t < NW1 * 128 + 128) {
        int q = t - NW1 * 128;
        int w = q / 64, i = q % 64;
        unsigned long long v = 0;
        for (int b = 0; b < 64; ++b)
            if (W2[i * 128 + w * 64 + b] != 0.0f) v |= (1ull << b);
        w2b[w * 64 + i] = v;
    } else if (t < NW1 * 128 + 128 + 10) {
        int i = t - (NW1 * 128 + 128);
        unsigned long long v = 0;
        for (int b = 0; b < 64; ++b)
            if (W3[i * 64 + b] != 0.0f) v |= (1ull << b);
        w3b[i] = v;
    }
}

// One block (256 threads) per sample.
__global__ __launch_bounds__(256) void net_fused(
        const float* __restrict__ x,        // (B,3,32,32)
        const float* __restrict__ conv_w,   // (1,3,5,5)
        const float* __restrict__ conv_b,   // (1,)
        const float* __restrict__ b1,       // (128,)
        const float* __restrict__ b2,       // (64,)
        const float* __restrict__ b3,       // (10,)
        const unsigned* __restrict__ w1t,   // [25][128]
        const unsigned long long* __restrict__ w2b, // [2][64]
        const unsigned long long* __restrict__ w3b, // [10]
        float* __restrict__ out)            // (B,10)
{
    // LDS: padded sample image (stride 36 floats keeps 16B alignment and
    // spreads conv-read banks), packed conv-output bits, h1 bits.
    __shared__ __align__(16) float xs[3 * 32 * 36];      // 13824 B
    __shared__ unsigned xb32[NW1];
    __shared__ unsigned long long h1w[2];

    const int t = threadIdx.x;
    const size_t samp = blockIdx.x;
    const float* xin = x + samp * 3072;

    // ---- stage sample into LDS (coalesced float4) ----
    #pragma unroll
    for (int k = 0; k < 3; ++k) {
        int f = k * 256 + t;                 // float4 index 0..767
        float4 g = ((const float4*)xin)[f];
        int fi = f * 4;
        int ch = fi >> 10;
        int rem = fi & 1023;
        int r = rem >> 5, c = rem & 31;
        *(float4*)&xs[ch * 1152 + r * 36 + c] = g;
    }
    if (t < NW1) xb32[t] = 0;
    __syncthreads();

    // ---- conv: 196 threads, each a 1x4 output strip ----
    if (t < 196) {
        const int r = t / 7, ct = t % 7, c0 = ct * 4;
        const float cb = conv_b[0];
        float acc0 = cb, acc1 = cb, acc2 = cb, acc3 = cb;
        #pragma unroll
        for (int ch = 0; ch < 3; ++ch) {
            float wv[25];
            #pragma unroll
            for (int k = 0; k < 25; ++k) wv[k] = conv_w[ch * 25 + k];
            #pragma unroll
            for (int kr = 0; kr < 5; ++kr) {
                const float* row = &xs[ch * 1152 + (r + kr) * 36 + c0];
                float4 a = *(const float4*)row;
                float4 b = *(const float4*)(row + 4);
                float in[8] = {a.x, a.y, a.z, a.w, b.x, b.y, b.z, b.w};
                #pragma unroll
                for (int kc = 0; kc < 5; ++kc) {
                    float w = wv[kr * 5 + kc];
                    acc0 += in[kc + 0] * w;
                    acc1 += in[kc + 1] * w;
                    acc2 += in[kc + 2] * w;
                    acc3 += in[kc + 3] * w;
                }
            }
        }
        int idx = r * 28 + c0;               // bit index, multiple of 4
        unsigned nib = (unsigned)(acc0 != 0.0f)
                     | ((unsigned)(acc1 != 0.0f) << 1)
                     | ((unsigned)(acc2 != 0.0f) << 2)
                     | ((unsigned)(acc3 != 0.0f) << 3);
        atomicOr(&xb32[idx >> 5], nib << (idx & 31));
    }
    __syncthreads();

    // ---- layer 1: 128 threads, xor-popcount over 25 words ----
    if (t < 128) {
        int s = 0;
        #pragma unroll
        for (int j = 0; j < NW1; ++j)
            s += __popc(xb32[j] ^ w1t[j * 128 + t]);
        float pre = (float)s + b1[t] - 392.0f;
        unsigned long long bal = __ballot(pre >= 0.0f);
        if ((t & 63) == 0) h1w[t >> 6] = bal;
    }
    __syncthreads();

    // ---- layers 2,3 + log_softmax: wave 0 only ----
    if (t < 64) {
        unsigned long long hA = h1w[0], hB = h1w[1];
        int s2 = __popcll(hA ^ w2b[t]) + __popcll(hB ^ w2b[64 + t]);
        float pre2 = (float)s2 + b2[t] - 64.0f;
        unsigned long long h2 = __ballot(pre2 >= 0.0f);

        float logit;
        if (t < 10) {
            int s3 = __popcll(h2 ^ w3b[t]);
            logit = (float)s3 + b3[t] - 32.0f;
        } else {
            logit = -INFINITY;
        }
        // reduce over lanes 0..15 (only group containing the 10 logits matters)
        float m = logit;
        #pragma unroll
        for (int off = 8; off >= 1; off >>= 1)
            m = fmaxf(m, __shfl_xor(m, off, 16));
        float e = (t < 10) ? expf(logit - m) : 0.0f;
        float ssum = e;
        #pragma unroll
        for (int off = 8; off >= 1; off >>= 1)
            ssum += __shfl_xor(ssum, off, 16);
        if (t < 10)
            out[samp * 10 + t] = logit - m - logf(ssum);
    }
}

extern "C" void kernel_launch(void* const* d_in, const int* in_sizes, int n_in,
                              void* d_out, int out_size, void* d_ws, size_t ws_size,
                              hipStream_t stream) {
    const float* x      = (const float*)d_in[0];
    const float* conv_w = (const float*)d_in[1];
    const float* conv_b = (const float*)d_in[2];
    const float* W1     = (const float*)d_in[3];
    const float* b1     = (const float*)d_in[4];
    const float* W2     = (const float*)d_in[5];
    const float* b2     = (const float*)d_in[6];
    const float* W3     = (const float*)d_in[7];
    const float* b3     = (const float*)d_in[8];
    float* out = (float*)d_out;

    const int B = in_sizes[0] / (3 * 32 * 32);

    // workspace layout
    unsigned* w1t            = (unsigned*)d_ws;                         // 12800 B
    unsigned long long* w2b  = (unsigned long long*)((char*)d_ws + 12800); // 1024 B
    unsigned long long* w3b  = (unsigned long long*)((char*)d_ws + 13824); // 80 B

    const int pack_threads = NW1 * 128 + 128 + 10;
    pack_weights<<<(pack_threads + 255) / 256, 256, 0, stream>>>(
        W1, W2, W3, w1t, w2b, w3b);

    net_fused<<<B, 256, 0, stream>>>(x, conv_w, conv_b, b1, b2, b3,
                                     w1t, w2b, w3b, out);
}